// Round 6
// baseline (1202.538 us; speedup 1.0000x reference)
//
#include <hip/hip_runtime.h>
#include <hip/hip_bf16.h>
#include <math.h>

typedef unsigned short u16;
typedef short v8s __attribute__((ext_vector_type(8)));
typedef float v4f __attribute__((ext_vector_type(4)));

#define SCALE_F 0.11180339887498949f
#define SCALE_L2 0.16129821534f   /* SCALE_F * log2(e) */

__device__ __forceinline__ float bf2f(u16 x) {
    unsigned int u = ((unsigned int)x) << 16;
    return __builtin_bit_cast(float, u);
}
__device__ __forceinline__ u16 f2bf(float f) {
    unsigned int u = __builtin_bit_cast(unsigned int, f);
    unsigned int r = (u + 0x7FFFu + ((u >> 16) & 1u)) >> 16;
    return (u16)r;
}
__device__ __forceinline__ float scrub(float v) {
    return (fabsf(v) < 1e30f) ? v : 0.f;
}
__device__ __forceinline__ v8s zero8() {
    union { v8s v; short s[8]; } t;
#pragma unroll
    for (int i = 0; i < 8; i++) t.s[i] = 0;
    return t.v;
}
// async global->LDS, 16B per lane; LDS dest = (wave-uniform base) + lane*16
__device__ __forceinline__ void glds16(const void* g, void* s) {
    __builtin_amdgcn_global_load_lds(
        (const __attribute__((address_space(1))) unsigned int*)g,
        (__attribute__((address_space(3))) unsigned int*)s, 16, 0, 0);
}

// ---------------------------------------------------------------------------
// convX: f32 -> bf16 elementwise (n % 4 == 0)
// ---------------------------------------------------------------------------
__global__ void convX_kernel(const float* __restrict__ X, u16* __restrict__ Xb, int n)
{
    int i = (blockIdx.x * 256 + threadIdx.x) * 4;
    if (i >= n) return;
    float4 v = *(const float4*)(X + i);
    u16 o[4] = { f2bf(v.x), f2bf(v.y), f2bf(v.z), f2bf(v.w) };
    *(uint2*)(Xb + i) = *(uint2*)o;
}

// ---------------------------------------------------------------------------
// convT: W f32 [K][N] -> WT bf16 [N][K]  (LDS 32x32 tile transpose)
// ---------------------------------------------------------------------------
__global__ __launch_bounds__(256) void convT_kernel(
    const float* __restrict__ W, u16* __restrict__ WT, int K, int N)
{
    __shared__ float t[32][33];
    int n0 = blockIdx.x * 32, k0 = blockIdx.y * 32;
    int tx = threadIdx.x & 31, ty = threadIdx.x >> 5;
    for (int i = ty; i < 32; i += 8) {
        int k = k0 + i, n = n0 + tx;
        t[i][tx] = (k < K && n < N) ? W[(size_t)k * N + n] : 0.f;
    }
    __syncthreads();
    for (int i = ty; i < 32; i += 8) {
        int n = n0 + i, k = k0 + tx;
        if (n < N && k < K) WT[(size_t)n * K + k] = f2bf(t[tx][i]);
    }
}

// ---------------------------------------------------------------------------
// xmean
// ---------------------------------------------------------------------------
__global__ void xmean_kernel(const float* __restrict__ X, float* __restrict__ Xm)
{
    int c = blockIdx.x * 256 + threadIdx.x;
    if (c >= 2560) return;
    int g = blockIdx.y;
    const float* base = X + (size_t)g * 32 * 2560 + c;
    float s = 0.f;
#pragma unroll 4
    for (int j = 0; j < 32; j++) s += base[(size_t)j * 2560];
    Xm[(size_t)g * 2560 + c] = s * (1.f / 32.f);
}

// ---------------------------------------------------------------------------
// Split-precision GEMM (bf16x3 ~ f32): C = A[M,K]@B[K,N] + bias. (kmean only)
// ---------------------------------------------------------------------------
__global__ __launch_bounds__(256) void gemmS_kernel(
    const float* __restrict__ A, const float* __restrict__ B,
    const float* __restrict__ bias, int M, int N, int K, float* __restrict__ outf)
{
    __shared__ __align__(16) u16 Ah[64][32], Al[64][32];
    __shared__ __align__(16) u16 Bh[64][32], Bl[64][32];
    const int tid = threadIdx.x;
    const int bm = blockIdx.x * 64, bn = blockIdx.y * 64;
    const int w = tid >> 6, lane = tid & 63;
    const int quad = lane >> 4, l = lane & 15;
    v4f acc[4];
#pragma unroll
    for (int nt = 0; nt < 4; nt++)
#pragma unroll
        for (int r = 0; r < 4; r++) acc[nt][r] = 0.f;
    const int ar = tid >> 2, ak = (tid & 3) * 8;
    const int kr = tid >> 3, nc = (tid & 7) * 8;
    for (int k0 = 0; k0 < K; k0 += 32) {
        float4 a0 = *(const float4*)(A + (size_t)(bm + ar) * K + (k0 + ak));
        float4 a1 = *(const float4*)(A + (size_t)(bm + ar) * K + (k0 + ak) + 4);
        float4 b0 = *(const float4*)(B + (size_t)(k0 + kr) * N + (bn + nc));
        float4 b1 = *(const float4*)(B + (size_t)(k0 + kr) * N + (bn + nc) + 4);
        float av[8] = {a0.x,a0.y,a0.z,a0.w,a1.x,a1.y,a1.z,a1.w};
        float bv[8] = {b0.x,b0.y,b0.z,b0.w,b1.x,b1.y,b1.z,b1.w};
        __syncthreads();
#pragma unroll
        for (int j = 0; j < 8; j++) {
            u16 h = f2bf(av[j]);
            Ah[ar][ak + j] = h; Al[ar][ak + j] = f2bf(av[j] - bf2f(h));
            u16 g = f2bf(bv[j]);
            Bh[nc + j][kr] = g; Bl[nc + j][kr] = f2bf(bv[j] - bf2f(g));
        }
        __syncthreads();
        v8s ah = *(const v8s*)(&Ah[w * 16 + l][quad * 8]);
        v8s al = *(const v8s*)(&Al[w * 16 + l][quad * 8]);
#pragma unroll
        for (int nt = 0; nt < 4; nt++) {
            v8s bh = *(const v8s*)(&Bh[nt * 16 + l][quad * 8]);
            v8s bl = *(const v8s*)(&Bl[nt * 16 + l][quad * 8]);
            acc[nt] = __builtin_amdgcn_mfma_f32_16x16x32_bf16(ah, bh, acc[nt], 0, 0, 0);
            acc[nt] = __builtin_amdgcn_mfma_f32_16x16x32_bf16(ah, bl, acc[nt], 0, 0, 0);
            acc[nt] = __builtin_amdgcn_mfma_f32_16x16x32_bf16(al, bh, acc[nt], 0, 0, 0);
        }
    }
#pragma unroll
    for (int nt = 0; nt < 4; nt++) {
        int col = bn + nt * 16 + l;
        float bvs = bias[col];
#pragma unroll
        for (int r = 0; r < 4; r++) {
            int row = bm + w * 16 + quad * 4 + r;
            outf[(size_t)row * N + col] = scrub(acc[nt][r] + bvs);
        }
    }
}

// ---------------------------------------------------------------------------
// m1
// ---------------------------------------------------------------------------
__global__ __launch_bounds__(256) void m1_kernel(
    const float* __restrict__ Wq, const float* __restrict__ km,
    u16* __restrict__ M1hT, u16* __restrict__ M1lT)
{
    __shared__ float Ws[64][81];
    __shared__ float Ks[32][80];
    int k0 = blockIdx.x * 64, h = blockIdx.y, b = blockIdx.z;
    int tid = threadIdx.x;
    for (int i = tid; i < 64 * 80; i += 256) {
        int kk = i / 80, dd = i - kk * 80;
        Ws[kk][dd] = Wq[(size_t)(k0 + kk) * 2560 + h * 80 + dd];
    }
    for (int i = tid; i < 32 * 80; i += 256) {
        int bl = i / 80, dd = i - bl * 80;
        Ks[bl][dd] = km[(size_t)((b << 5) + bl) * 2560 + h * 80 + dd];
    }
    __syncthreads();
    int kk = tid & 63, bq4 = tid >> 6;
    for (int bt = 0; bt < 8; bt++) {
        int blk = bt * 4 + bq4;
        float s = 0.f;
#pragma unroll 8
        for (int d = 0; d < 80; d++) s += Ws[kk][d] * Ks[blk][d];
        u16 hi = f2bf(s);
        size_t o = (size_t)(b * 1024 + h * 32 + blk) * 2560 + k0 + kk;
        M1hT[o] = hi;
        M1lT[o] = f2bf(s - bf2f(hi));
    }
}

// bias3
__global__ void bias3_kernel(const float* __restrict__ bq, const float* __restrict__ km,
                             float* __restrict__ bias3)
{
    int i = blockIdx.x * 256 + threadIdx.x;
    if (i >= 2048) return;
    int b = i >> 10, hb = i & 1023, h = hb >> 5, blk = hb & 31;
    float s = 0.f;
    for (int d = 0; d < 80; d++) s += bq[h * 80 + d] * km[(size_t)((b << 5) + blk) * 2560 + h * 80 + d];
    bias3[i] = s;
}

// ---------------------------------------------------------------------------
// gemmS2: BS = A(f32, split inline) @ BT(pre-split bf16 [N][K])^T + bias -> f32
// 2-phase pipeline: B via glds16 double-buffer; A via register prefetch.
// ---------------------------------------------------------------------------
__global__ __launch_bounds__(256) void gemmS2_kernel(
    const float* __restrict__ A, const u16* __restrict__ BhT, const u16* __restrict__ BlT,
    const float* __restrict__ bias, int M, int N, int K, float* __restrict__ outf)
{
    __shared__ __align__(16) u16 Ah[2][64][32], Al[2][64][32];
    __shared__ __align__(16) u16 Bh[2][64][32], Bl[2][64][32];
    const int tid = threadIdx.x;
    const int z = blockIdx.z;
    const float* Az = A + (size_t)z * 1024 * 2560;
    const u16* Bhz = BhT + (size_t)z * 1024 * 2560;
    const u16* Blz = BlT + (size_t)z * 1024 * 2560;
    const float* biasz = bias + (size_t)z * 1024;
    float* outz = outf + (size_t)z * 1024 * 1024;
    const int bm = blockIdx.x * 64, bn = blockIdx.y * 64;
    const int w = tid >> 6, lane = tid & 63;
    const int quad = lane >> 4, l = lane & 15;
    v4f acc[4];
#pragma unroll
    for (int nt = 0; nt < 4; nt++)
#pragma unroll
        for (int r = 0; r < 4; r++) acc[nt][r] = 0.f;
    const int ar = tid >> 2, ak = (tid & 3) * 8;
    const float* ApF = Az + (size_t)(bm + ar) * K + ak;
    const u16* BpH = Bhz + (size_t)(bn + ar) * K + ak;
    const u16* BpL = Blz + (size_t)(bn + ar) * K + ak;
    char* BhB = (char*)Bh;
    char* BlB = (char*)Bl;
    const int NT = K >> 5;
    glds16(BpH, BhB + w * 1024);
    glds16(BpL, BlB + w * 1024);
    float4 a0 = *(const float4*)(ApF);
    float4 a1 = *(const float4*)(ApF + 4);
    __syncthreads();
    for (int t = 0; t < NT; t++) {
        const int cur = t & 1;
        const int nxt = cur ^ 1;
        if (t + 1 < NT) {
            int k0n = (t + 1) << 5;
            glds16(BpH + k0n, BhB + nxt * 4096 + w * 1024);
            glds16(BpL + k0n, BlB + nxt * 4096 + w * 1024);
        }
        float av[8] = {a0.x, a0.y, a0.z, a0.w, a1.x, a1.y, a1.z, a1.w};
        if (t + 1 < NT) {
            int k0n = (t + 1) << 5;
            a0 = *(const float4*)(ApF + k0n);
            a1 = *(const float4*)(ApF + k0n + 4);
        }
#pragma unroll
        for (int j = 0; j < 8; j++) {
            u16 h = f2bf(av[j]);
            Ah[cur][ar][ak + j] = h;
            Al[cur][ar][ak + j] = f2bf(av[j] - bf2f(h));
        }
        v8s ah = *(const v8s*)(&Ah[cur][w * 16 + l][quad * 8]);
        v8s al2 = *(const v8s*)(&Al[cur][w * 16 + l][quad * 8]);
#pragma unroll
        for (int nt = 0; nt < 4; nt++) {
            v8s bh = *(const v8s*)(&Bh[cur][nt * 16 + l][quad * 8]);
            v8s bl = *(const v8s*)(&Bl[cur][nt * 16 + l][quad * 8]);
            acc[nt] = __builtin_amdgcn_mfma_f32_16x16x32_bf16(ah, bh, acc[nt], 0, 0, 0);
            acc[nt] = __builtin_amdgcn_mfma_f32_16x16x32_bf16(ah, bl, acc[nt], 0, 0, 0);
            acc[nt] = __builtin_amdgcn_mfma_f32_16x16x32_bf16(al2, bh, acc[nt], 0, 0, 0);
        }
        __syncthreads();
    }
#pragma unroll
    for (int nt = 0; nt < 4; nt++) {
        int col = bn + nt * 16 + l;
        float bvs = biasz[col];
#pragma unroll
        for (int r = 0; r < 4; r++) {
            int row = bm + w * 16 + quad * 4 + r;
            outz[(size_t)row * N + col] = scrub(acc[nt][r] + bvs);
        }
    }
}

// ---------------------------------------------------------------------------
// gemmB: C = act(A[M,K]@BT[N,K]^T + bias). 2-phase glds16 double-buffer.
// ---------------------------------------------------------------------------
__global__ __launch_bounds__(256) void gemmB_kernel(
    const u16* __restrict__ A, const u16* __restrict__ Al2, const u16* __restrict__ BT,
    const float* __restrict__ bias, int M, int N, int K, int act, int ldc,
    u16* __restrict__ outb, float* __restrict__ outf, u16* __restrict__ outT)
{
    __shared__ __align__(16) u16 As[2][64][32];
    __shared__ __align__(16) u16 As2[2][64][32];
    __shared__ __align__(16) u16 Bs[2][64][32];
    const int tid = threadIdx.x;
    const int bm = blockIdx.x * 64, bn = blockIdx.y * 64;
    const int w = tid >> 6, lane = tid & 63;
    const int quad = lane >> 4, l = lane & 15;
    v4f acc[4];
#pragma unroll
    for (int nt = 0; nt < 4; nt++)
#pragma unroll
        for (int r = 0; r < 4; r++) acc[nt][r] = 0.f;
    const int srow = w * 16 + (lane >> 2);
    const int kcol = (lane & 3) * 8;
    const int brow = (bn + srow < N) ? (bn + srow) : (N - 1);
    const u16* Ap = A + (size_t)(bm + srow) * K + kcol;
    const u16* Bp = BT + (size_t)brow * K + kcol;
    const u16* A2p = Al2 ? (Al2 + (size_t)(bm + srow) * K + kcol) : nullptr;
    char* AsB = (char*)As;
    char* As2B = (char*)As2;
    char* BsB = (char*)Bs;
    const int NT = K >> 5;
    glds16(Ap, AsB + w * 1024);
    glds16(Bp, BsB + w * 1024);
    if (Al2) glds16(A2p, As2B + w * 1024);
    __syncthreads();
    for (int t = 0; t < NT; t++) {
        const int cur = t & 1;
        const int nxt = cur ^ 1;
        if (t + 1 < NT) {
            int k0n = (t + 1) << 5;
            glds16(Ap + k0n, AsB + nxt * 4096 + w * 1024);
            glds16(Bp + k0n, BsB + nxt * 4096 + w * 1024);
            if (Al2) glds16(A2p + k0n, As2B + nxt * 4096 + w * 1024);
        }
        v8s af = *(const v8s*)(&As[cur][w * 16 + l][quad * 8]);
#pragma unroll
        for (int nt = 0; nt < 4; nt++) {
            v8s bf = *(const v8s*)(&Bs[cur][nt * 16 + l][quad * 8]);
            acc[nt] = __builtin_amdgcn_mfma_f32_16x16x32_bf16(af, bf, acc[nt], 0, 0, 0);
        }
        if (Al2) {
            v8s af2 = *(const v8s*)(&As2[cur][w * 16 + l][quad * 8]);
#pragma unroll
            for (int nt = 0; nt < 4; nt++) {
                v8s bf = *(const v8s*)(&Bs[cur][nt * 16 + l][quad * 8]);
                acc[nt] = __builtin_amdgcn_mfma_f32_16x16x32_bf16(af2, bf, acc[nt], 0, 0, 0);
            }
        }
        __syncthreads();
    }
#pragma unroll
    for (int nt = 0; nt < 4; nt++) {
        int col = bn + nt * 16 + l;
        if (col < N) {
            float bvs = bias[col];
#pragma unroll
            for (int r = 0; r < 4; r++) {
                int row = bm + w * 16 + quad * 4 + r;
                float c = acc[nt][r] + bvs;
                if (act == 1) c = 0.5f * c * (1.0f + erff(c * 0.70710678118654752f));
                c = scrub(c);
                if (outf) outf[(size_t)row * ldc + col] = c;
                if (outb) outb[(size_t)row * ldc + col] = f2bf(c);
                if (outT) {
                    int bb = row >> 10, s = row & 1023;
                    int hh = col / 80, dd = col - hh * 80;
                    outT[((size_t)((bb << 5) + hh) * 96 + dd) * 1024 + s] = f2bf(c);
                }
            }
        }
    }
}

// ---------------------------------------------------------------------------
// gatherF / gatherFT
// ---------------------------------------------------------------------------
__global__ void gatherF_kernel(const u16* __restrict__ src, const float* __restrict__ pos,
                               u16* __restrict__ F)
{
    int row = blockIdx.y;
    int col = blockIdx.x * 256 + threadIdx.x;
    if (col >= 2560) return;
    int b = row >> 10, h = (row >> 5) & 31, blk = row & 31;
    int j = col / 80, d = col - j * 80;
    float v = bf2f(src[(size_t)(b * 1024 + blk * 32 + j) * 2560 + h * 80 + d]) + pos[col];
    F[(size_t)row * 2560 + col] = f2bf(v);
}
__global__ void gatherFT_kernel(const u16* __restrict__ vt, const float* __restrict__ pos,
                                u16* __restrict__ F)
{
    int row = blockIdx.y;
    int col = blockIdx.x * 256 + threadIdx.x;
    if (col >= 2560) return;
    int b = row >> 10, h = (row >> 5) & 31, blk = row & 31;
    int j = col / 80, d = col - j * 80;
    float v = bf2f(vt[((size_t)((b << 5) + h) * 96 + d) * 1024 + blk * 32 + j]) + pos[col];
    F[(size_t)row * 2560 + col] = f2bf(v);
}

// ---------------------------------------------------------------------------
// gates
// ---------------------------------------------------------------------------
__global__ __launch_bounds__(256) void gates_kernel(
    const u16* __restrict__ gh, const float* __restrict__ W2,
    const float* __restrict__ b2, float* __restrict__ gates)
{
    int w = threadIdx.x >> 6, lane = threadIdx.x & 63;
    int token = blockIdx.x * 4 + w;
    float s0 = 0.f, s1 = 0.f, s2 = 0.f;
    for (int i = lane; i < 1280; i += 64) {
        float g = bf2f(gh[(size_t)token * 1280 + i]);
        s0 += g * W2[i * 3 + 0];
        s1 += g * W2[i * 3 + 1];
        s2 += g * W2[i * 3 + 2];
    }
#pragma unroll
    for (int m = 1; m < 64; m <<= 1) {
        s0 += __shfl_xor(s0, m);
        s1 += __shfl_xor(s1, m);
        s2 += __shfl_xor(s2, m);
    }
    if (lane == 0) {
        gates[token * 3 + 0] = scrub(1.f / (1.f + expf(-(s0 + b2[0]))));
        gates[token * 3 + 1] = scrub(1.f / (1.f + expf(-(s1 + b2[1]))));
        gates[token * 3 + 2] = scrub(1.f / (1.f + expf(-(s2 + b2[2]))));
    }
}

// ---------------------------------------------------------------------------
// Fused NSA attention v6: one wave per (bh, 16-query tile).
// vs v3 (R5): (1) ALL __syncthreads removed -- single-wave block, in-wave LDS
// ordering via compiler lgkmcnt; kills the per-iteration vmcnt(0) barrier
// drain. (2) K fragments double-buffered across iterations (unroll-by-2,
// static names) so K(kb+1) loads hide under softmax+PV(kb). (3) V fragments
// early-issued at iteration top so softmax covers their latency.
// ---------------------------------------------------------------------------
#define KLOAD(K0,K1,K2,K3,K4,K5, kbv) do {                                    \
    size_t base_ = (size_t)(b * 1024 + (kbv) * 32) * 2560 + h * 80 + quad * 8;\
    const u16* p0_ = kbf + base_ + (size_t)l * 2560;                          \
    const u16* p1_ = kbf + base_ + (size_t)(16 + l) * 2560;                   \
    K0 = *(const v8s*)(p0_);                                                  \
    K1 = *(const v8s*)(p0_ + 32);                                             \
    K3 = *(const v8s*)(p1_);                                                  \
    K4 = *(const v8s*)(p1_ + 32);                                             \
    if (quad < 2) { K2 = *(const v8s*)(p0_ + 64); K5 = *(const v8s*)(p1_ + 64); } \
    else { K2 = zero8(); K5 = zero8(); }                                      \
} while (0)

#define ATTN_ITER(kbv, K0,K1,K2,K3,K4,K5, DOPRE, N0,N1,N2,N3,N4,N5) do {      \
    const int kb_ = (kbv);                                                    \
    const u16* vp_ = vtp + kb_ * 32 + quad * 8;                               \
    v8s va0_ = *(const v8s*)(vp_ + (size_t)(l) * 1024);                       \
    v8s va1_ = *(const v8s*)(vp_ + (size_t)(16 + l) * 1024);                  \
    v8s va2_ = *(const v8s*)(vp_ + (size_t)(32 + l) * 1024);                  \
    v8s va3_ = *(const v8s*)(vp_ + (size_t)(48 + l) * 1024);                  \
    v8s va4_ = *(const v8s*)(vp_ + (size_t)(64 + l) * 1024);                  \
    v4f s0_, s1_;                                                             \
    _Pragma("unroll")                                                         \
    for (int r = 0; r < 4; r++) { s0_[r] = 0.f; s1_[r] = 0.f; }               \
    s0_ = __builtin_amdgcn_mfma_f32_16x16x32_bf16(qfrag[0], K0, s0_, 0, 0, 0);\
    s0_ = __builtin_amdgcn_mfma_f32_16x16x32_bf16(qfrag[1], K1, s0_, 0, 0, 0);\
    s0_ = __builtin_amdgcn_mfma_f32_16x16x32_bf16(qfrag[2], K2, s0_, 0, 0, 0);\
    s1_ = __builtin_amdgcn_mfma_f32_16x16x32_bf16(qfrag[0], K3, s1_, 0, 0, 0);\
    s1_ = __builtin_amdgcn_mfma_f32_16x16x32_bf16(qfrag[1], K4, s1_, 0, 0, 0);\
    s1_ = __builtin_amdgcn_mfma_f32_16x16x32_bf16(qfrag[2], K5, s1_, 0, 0, 0);\
    if (DOPRE) { KLOAD(N0, N1, N2, N3, N4, N5, kb_ + 1); }                    \
    float x0a_[4], x1a_[4], pmax_[4];                                         \
    float needmax_ = NEG;                                                     \
    _Pragma("unroll")                                                         \
    for (int r = 0; r < 4; r++) {                                             \
        x0a_[r] = s0_[r] * SCALE_L2; x1a_[r] = s1_[r] * SCALE_L2;             \
        float mb_ = fmaxf(x0a_[r], x1a_[r]);                                  \
        _Pragma("unroll")                                                     \
        for (int m = 1; m < 16; m <<= 1) mb_ = fmaxf(mb_, __shfl_xor(mb_, m));\
        pmax_[r] = mb_;                                                       \
        needmax_ = fmaxf(needmax_, mb_ - m_w[r]);                             \
    }                                                                         \
    if (__all(needmax_ <= 8.0f)) {                                            \
        _Pragma("unroll")                                                     \
        for (int r = 0; r < 4; r++) {                                         \
            float p0_ = exp2f(x0a_[r] - m_w[r]), p1_ = exp2f(x1a_[r] - m_w[r]); \
            Pw[quad * 4 + r][l]      = f2bf(p0_);                             \
            Pw[quad * 4 + r][l + 16] = f2bf(p1_);                             \
            float st_ = p0_ + p1_;                                            \
            _Pragma("unroll")                                                 \
            for (int m = 1; m < 16; m <<= 1) st_ += __shfl_xor(st_, m);       \
            l_w[r] += st_;                                                    \
            if ((selm[r] >> kb_) & 1u) l_s[r] += st_;                         \
        }                                                                     \
    } else {                                                                  \
        float alw_[4];                                                        \
        _Pragma("unroll")                                                     \
        for (int r = 0; r < 4; r++) {                                         \
            float mn_ = fmaxf(m_w[r], pmax_[r]);                              \
            alw_[r] = exp2f(m_w[r] - mn_);                                    \
            m_w[r] = mn_;                                                     \
            float p0_ = exp2f(x0a_[r] - mn_), p1_ = exp2f(x1a_[r] - mn_);     \
            Pw[quad * 4 + r][l]      = f2bf(p0_);                             \
            Pw[quad * 4 + r][l + 16] = f2bf(p1_);                             \
            float st_ = p0_ + p1_;                                            \
            _Pragma("unroll")                                                 \
            for (int m = 1; m < 16; m <<= 1) st_ += __shfl_xor(st_, m);       \
            l_w[r] = l_w[r] * alw_[r] + st_;                                  \
            l_s[r] = l_s[r] * alw_[r] + (((selm[r] >> kb_) & 1u) ? st_ : 0.f);\
        }                                                                     \
        _Pragma("unroll")                                                     \
        for (int t = 0; t < 5; t++)                                           \
            _Pragma("unroll")                                                 \
            for (int r = 0; r < 4; r++) { aw[t][r] *= alw_[r]; as_[t][r] *= alw_[r]; } \
    }                                                                         \
    v8s pwa_ = *(const v8s*)(&Pw[l][quad * 8]);                               \
    v8s psa_ = ((selm_l >> kb_) & 1u) ? pwa_ : zero8();                       \
    aw[0]  = __builtin_amdgcn_mfma_f32_16x16x32_bf16(pwa_, va0_, aw[0], 0, 0, 0); \
    as_[0] = __builtin_amdgcn_mfma_f32_16x16x32_bf16(psa_, va0_, as_[0], 0, 0, 0); \
    aw[1]  = __builtin_amdgcn_mfma_f32_16x16x32_bf16(pwa_, va1_, aw[1], 0, 0, 0); \
    as_[1] = __builtin_amdgcn_mfma_f32_16x16x32_bf16(psa_, va1_, as_[1], 0, 0, 0); \
    aw[2]  = __builtin_amdgcn_mfma_f32_16x16x32_bf16(pwa_, va2_, aw[2], 0, 0, 0); \
    as_[2] = __builtin_amdgcn_mfma_f32_16x16x32_bf16(psa_, va2_, as_[2], 0, 0, 0); \
    aw[3]  = __builtin_amdgcn_mfma_f32_16x16x32_bf16(pwa_, va3_, aw[3], 0, 0, 0); \
    as_[3] = __builtin_amdgcn_mfma_f32_16x16x32_bf16(psa_, va3_, as_[3], 0, 0, 0); \
    aw[4]  = __builtin_amdgcn_mfma_f32_16x16x32_bf16(pwa_, va4_, aw[4], 0, 0, 0); \
    as_[4] = __builtin_amdgcn_mfma_f32_16x16x32_bf16(psa_, va4_, as_[4], 0, 0, 0); \
} while (0)

__global__ __launch_bounds__(64) void attn_kernel(
    const u16* __restrict__ qb, const u16* __restrict__ kbf,
    const u16* __restrict__ vt, const u16* __restrict__ kc,
    const u16* __restrict__ vc, const float* __restrict__ BSf,
    const float* __restrict__ gates, u16* __restrict__ comb, u16* __restrict__ combl)
{
    const int lane = threadIdx.x, quad = lane >> 4, l = lane & 15;
    const int qt = blockIdx.x, bh = blockIdx.y, b = bh >> 5, h = bh & 31;
    const float NEG = -1e30f;

    __shared__ float bs[16][33];
    __shared__ unsigned int selmask[16];
    __shared__ __align__(16) u16 Pw[16][40];
    __shared__ float ocn[16][80];

    // ---- block scores from precomputed BS (f32-accurate) ----
    {
        const float* bsrow = BSf + ((size_t)b * 1024 + qt * 16 + l) * 1024 + h * 32 + quad * 8;
#pragma unroll
        for (int i = 0; i < 8; i++) bs[l][quad * 8 + i] = bsrow[i] * SCALE_F;
    }
    if (lane < 16) {
        unsigned int mask = 0u;
        for (int it = 0; it < 16; it++) {
            float best = NEG; int bi = -1;
            for (int n = 0; n < 32; n++) {
                if (((mask >> n) & 1u) == 0u && bs[lane][n] > best) { best = bs[lane][n]; bi = n; }
            }
            if (bi < 0) { for (int n = 0; n < 32; n++) if (((mask >> n) & 1u) == 0u) { bi = n; break; } }
            mask |= (1u << bi);
        }
        selmask[lane] = mask;
    }
    const unsigned int selm_l = selmask[l];   // mask for PV A-fragment row (query l)
    unsigned int selm[4];
#pragma unroll
    for (int r = 0; r < 4; r++) selm[r] = selmask[quad * 4 + r];  // mask for C-row q=quad*4+r

    // ---- Q fragments ----
    v8s qfrag[3];
    {
        const u16* qrow = qb + (size_t)(b * 1024 + qt * 16 + l) * 2560 + h * 80;
#pragma unroll
        for (int c = 0; c < 3; c++) {
            if (c == 2 && quad >= 2) { qfrag[c] = zero8(); }
            else qfrag[c] = *(const v8s*)(qrow + c * 32 + quad * 8);
        }
    }

    // ---- compressed branch; result normalized+g0-folded into ocn LDS ----
    {
        v4f oc[5];
#pragma unroll
        for (int t = 0; t < 5; t++)
#pragma unroll
            for (int r = 0; r < 4; r++) oc[t][r] = 0.f;
        float l_c[4];
        v4f s0, s1;
#pragma unroll
        for (int r = 0; r < 4; r++) { s0[r] = 0.f; s1[r] = 0.f; }
#pragma unroll
        for (int c = 0; c < 3; c++) {
            v8s b0, b1;
            if (c == 2 && quad >= 2) { b0 = zero8(); b1 = zero8(); }
            else {
                b0 = *(const v8s*)(kc + (size_t)(bh * 32 + l) * 80 + c * 32 + quad * 8);
                b1 = *(const v8s*)(kc + (size_t)(bh * 32 + 16 + l) * 80 + c * 32 + quad * 8);
            }
            s0 = __builtin_amdgcn_mfma_f32_16x16x32_bf16(qfrag[c], b0, s0, 0, 0, 0);
            s1 = __builtin_amdgcn_mfma_f32_16x16x32_bf16(qfrag[c], b1, s1, 0, 0, 0);
        }
#pragma unroll
        for (int r = 0; r < 4; r++) {
            float x0 = s0[r] * SCALE_L2, x1 = s1[r] * SCALE_L2;
            float mx = fmaxf(x0, x1);
#pragma unroll
            for (int m = 1; m < 16; m <<= 1) mx = fmaxf(mx, __shfl_xor(mx, m));
            float p0 = exp2f(x0 - mx), p1 = exp2f(x1 - mx);
            float sm = p0 + p1;
#pragma unroll
            for (int m = 1; m < 16; m <<= 1) sm += __shfl_xor(sm, m);
            l_c[r] = sm;
            Pw[quad * 4 + r][l]      = f2bf(p0);
            Pw[quad * 4 + r][l + 16] = f2bf(p1);
        }
        v8s pa = *(const v8s*)(&Pw[l][quad * 8]);
#pragma unroll
        for (int t = 0; t < 5; t++) {
            union { v8s v; short s[8]; } vf;
#pragma unroll
            for (int j = 0; j < 8; j++)
                vf.s[j] = (short)vc[(size_t)(bh * 32 + quad * 8 + j) * 80 + t * 16 + l];
            oc[t] = __builtin_amdgcn_mfma_f32_16x16x32_bf16(pa, vf.v, oc[t], 0, 0, 0);
        }
#pragma unroll
        for (int r = 0; r < 4; r++) {
            int token = b * 1024 + qt * 16 + quad * 4 + r;
            float g0 = gates[token * 3 + 0];
            float fc = g0 / fmaxf(l_c[r], 1e-30f);
#pragma unroll
            for (int t = 0; t < 5; t++) ocn[quad * 4 + r][t * 16 + l] = oc[t][r] * fc;
        }
    }

    // ---- flash loop: window + selection, K double-buffered, V early-issue ----
    v4f aw[5], as_[5];
    float m_w[4], l_w[4], l_s[4];
#pragma unroll
    for (int r = 0; r < 4; r++) { m_w[r] = NEG; l_w[r] = 0.f; l_s[r] = 0.f; }
#pragma unroll
    for (int t = 0; t < 5; t++)
#pragma unroll
        for (int r = 0; r < 4; r++) { aw[t][r] = 0.f; as_[t][r] = 0.f; }

    const u16* vtp = vt + (size_t)bh * 96 * 1024;

    v8s ka0, ka1, ka2, ka3, ka4, ka5;
    v8s kn0 = zero8(), kn1 = zero8(), kn2 = zero8(),
        kn3 = zero8(), kn4 = zero8(), kn5 = zero8();
    KLOAD(ka0, ka1, ka2, ka3, ka4, ka5, 0);

    for (int kb2 = 0; kb2 < 32; kb2 += 2) {
        ATTN_ITER(kb2,     ka0, ka1, ka2, ka3, ka4, ka5, true,
                           kn0, kn1, kn2, kn3, kn4, kn5);
        ATTN_ITER(kb2 + 1, kn0, kn1, kn2, kn3, kn4, kn5, (kb2 + 2 < 32),
                           ka0, ka1, ka2, ka3, ka4, ka5);
    }

    // ---- gate-combine + split store ----
#pragma unroll
    for (int r = 0; r < 4; r++) {
        int token = b * 1024 + qt * 16 + quad * 4 + r;
        float g1 = gates[token * 3 + 1], g2 = gates[token * 3 + 2];
        float fw = g2 / fmaxf(l_w[r], 1e-30f);
        float fs = g1 / fmaxf(l_s[r], 1e-30f);
#pragma unroll
        for (int t = 0; t < 5; t++) {
            float val = ocn[quad * 4 + r][t * 16 + l] + fs * as_[t][r] + fw * aw[t][r];
            val = scrub(val);
            u16 hi = f2bf(val);
            size_t o = (size_t)token * 2560 + h * 80 + t * 16 + l;
            comb[o] = hi;
            combl[o] = f2bf(val - bf2f(hi));
        }
    }
}

// ---------------------------------------------------------------------------
extern "C" void kernel_launch(void* const* d_in, const int* in_sizes, int n_in,
                              void* d_out, int out_size, void* d_ws, size_t ws_size,
                              hipStream_t stream)
{
    (void)in_sizes; (void)n_in; (void)out_size; (void)ws_size;

    const float* X   = (const float*)d_in[0];
    const float* Wq  = (const float*)d_in[1];
    const float* bq  = (const float*)d_in[2];
    const float* Wk  = (const float*)d_in[3];
    const float* bk  = (const float*)d_in[4];
    const float* Wv  = (const float*)d_in[5];
    const float* bv  = (const float*)d_in[6];
    const float* Wo  = (const float*)d_in[7];
    const float* bo  = (const float*)d_in[8];
    const float* pos = (const float*)d_in[9];
    const float* cW1 = (const float*)d_in[10];
    const float* cb1 = (const float*)d_in[11];
    const float* cW2 = (const float*)d_in[12];
    const float* cb2 = (const float*)d_in[13];
    const float* gW1 = (const float*)d_in[14];
    const float* gb1 = (const float*)d_in[15];
    const float* gW2 = (const float*)d_in[16];
    const float* gb2 = (const float*)d_in[17];

    char* ws = (char*)d_ws;
    size_t off = 0;
    auto alloc = [&](size_t bytes) -> void* {
        void* p = ws + off;
        off += (bytes + 255) & ~(size_t)255;
        return p;
    };
    u16*   Xb     = (u16*)  alloc(2048ull * 2560 * 2);
    u16*   WqT    = (u16*)  alloc(2560ull * 2560 * 2);
    u16*   WkT    = (u16*)  alloc(2560ull * 2560 * 2);
    u16*   WvT    = (u16*)  alloc(2560ull * 2560 * 2);
    u16*   WoT    = (u16*)  alloc(2560ull * 2560 * 2);
    u16*   gW1T   = (u16*)  alloc(1280ull * 2560 * 2);
    u16*   cW1T   = (u16*)  alloc(320ull * 2560 * 2);
    u16*   cW2T   = (u16*)  alloc(96ull * 320 * 2);
    float* Xm     = (float*)alloc(64ull * 2560 * 4);
    float* kmeanS = (float*)alloc(64ull * 2560 * 4);
    u16*   M1hT   = (u16*)  alloc(2048ull * 2560 * 2);
    u16*   M1lT   = (u16*)  alloc(2048ull * 2560 * 2);
    float* bias3  = (float*)alloc(2048ull * 4);
    u16*   qbuf   = (u16*)  alloc(2048ull * 2560 * 2);
    u16*   kbf    = (u16*)  alloc(2048ull * 2560 * 2);
    u16*   vtb    = (u16*)  alloc(64ull * 96 * 1024 * 2);
    u16*   combl  = (u16*)  alloc(2048ull * 2560 * 2);
    char*  R1     = (char*) alloc(12ull * 1024 * 1024);
    u16*   gh     = (u16*)R1;
    u16*   Fb     = (u16*)R1;
    u16*   H1     = (u16*)(R1 + 10ull * 1024 * 1024);
    u16*   combb  = (u16*)R1;
    u16*   KC     = (u16*)  alloc(2048ull * 80 * 2);
    u16*   VC     = (u16*)  alloc(2048ull * 80 * 2);
    float* gatesf = (float*)alloc(2048ull * 3 * 4);
    float* BSf    = (float*)d_out;

    dim3 blk(256);
    convX_kernel<<<2048 * 2560 / 4 / 256, blk, 0, stream>>>(X, Xb, 2048 * 2560);
    convT_kernel<<<dim3(80, 80), blk, 0, stream>>>(Wq, WqT, 2560, 2560);
    convT_kernel<<<dim3(80, 80), blk, 0, stream>>>(Wk, WkT, 2560, 2560);
    convT_kernel<<<dim3(80, 80), blk, 0, stream>>>(Wv, WvT, 2560, 2560);
    convT_kernel<<<dim3(80, 80), blk, 0, stream>>>(Wo, WoT, 2560, 2560);
    convT_kernel<<<dim3(40, 80), blk, 0, stream>>>(gW1, gW1T, 2560, 1280);
    convT_kernel<<<dim3(10, 80), blk, 0, stream>>>(cW1, cW1T, 2560, 320);
    convT_kernel<<<dim3(3, 10), blk, 0, stream>>>(cW2, cW2T, 320, 80);
    xmean_kernel<<<dim3(10, 64), blk, 0, stream>>>(X, Xm);
    gemmS_kernel<<<dim3(1, 40), blk, 0, stream>>>(Xm, Wk, bk, 64, 2560, 2560, kmeanS);
    m1_kernel<<<dim3(40, 32, 2), blk, 0, stream>>>(Wq, kmeanS, M1hT, M1lT);
    bias3_kernel<<<8, blk, 0, stream>>>(bq, kmeanS, bias3);
    gemmS2_kernel<<<dim3(16, 16, 2), blk, 0, stream>>>(X, M1hT, M1lT, bias3, 1024, 1024, 2560, BSf);
    gemmB_kernel<<<dim3(32, 40), blk, 0, stream>>>(Xb, nullptr, WqT, bq, 2048, 2560, 2560, 0, 2560, qbuf, nullptr, nullptr);
    gemmB_kernel<<<dim3(32, 40), blk, 0, stream>>>(Xb, nullptr, WkT, bk, 2048, 2560, 2560, 0, 2560, kbf, nullptr, nullptr);
    gemmB_kernel<<<dim3(32, 40), blk, 0, stream>>>(Xb, nullptr, WvT, bv, 2048, 2560, 2560, 0, 2560, nullptr, nullptr, vtb);
    gemmB_kernel<<<dim3(32, 20), blk, 0, stream>>>(Xb, nullptr, gW1T, gb1, 2048, 1280, 2560, 1, 1280, gh, nullptr, nullptr);
    gates_kernel<<<512, blk, 0, stream>>>(gh, gW2, gb2, gatesf);
    gatherF_kernel<<<dim3(10, 2048), blk, 0, stream>>>(kbf, pos, Fb);
    gemmB_kernel<<<dim3(32, 5), blk, 0, stream>>>(Fb, nullptr, cW1T, cb1, 2048, 320, 2560, 1, 320, H1, nullptr, nullptr);
    gemmB_kernel<<<dim3(32, 2), blk, 0, stream>>>(H1, nullptr, cW2T, cb2, 2048, 80, 320, 0, 80, KC, nullptr, nullptr);
    gatherFT_kernel<<<dim3(10, 2048), blk, 0, stream>>>(vtb, pos, Fb);
    gemmB_kernel<<<dim3(32, 5), blk, 0, stream>>>(Fb, nullptr, cW1T, cb1, 2048, 320, 2560, 1, 320, H1, nullptr, nullptr);
    gemmB_kernel<<<dim3(32, 2), blk, 0, stream>>>(H1, nullptr, cW2T, cb2, 2048, 80, 320, 0, 80, VC, nullptr, nullptr);
    attn_kernel<<<dim3(64, 64), 64, 0, stream>>>(qbuf, kbf, vtb, KC, VC, BSf, gatesf, combb, combl);
    gemmB_kernel<<<dim3(32, 40), blk, 0, stream>>>(combb, combl, WoT, bo, 2048, 2560, 2560, 0, 2560, nullptr, (float*)d_out, nullptr);
}

// Round 7
// 1130.112 us; speedup vs baseline: 1.0641x; 1.0641x over previous
//
#include <hip/hip_runtime.h>
#include <hip/hip_bf16.h>
#include <math.h>

typedef unsigned short u16;
typedef short v8s __attribute__((ext_vector_type(8)));
typedef float v4f __attribute__((ext_vector_type(4)));

#define SCALE_F 0.11180339887498949f
#define SCALE_L2 0.16129821534f   /* SCALE_F * log2(e) */

__device__ __forceinline__ float bf2f(u16 x) {
    unsigned int u = ((unsigned int)x) << 16;
    return __builtin_bit_cast(float, u);
}
__device__ __forceinline__ u16 f2bf(float f) {
    unsigned int u = __builtin_bit_cast(unsigned int, f);
    unsigned int r = (u + 0x7FFFu + ((u >> 16) & 1u)) >> 16;
    return (u16)r;
}
__device__ __forceinline__ float scrub(float v) {
    return (fabsf(v) < 1e30f) ? v : 0.f;
}
__device__ __forceinline__ v8s zero8() {
    union { v8s v; short s[8]; } t;
#pragma unroll
    for (int i = 0; i < 8; i++) t.s[i] = 0;
    return t.v;
}
// async global->LDS, 16B per lane; LDS dest = (wave-uniform base) + lane*16
__device__ __forceinline__ void glds16(const void* g, void* s) {
    __builtin_amdgcn_global_load_lds(
        (const __attribute__((address_space(1))) unsigned int*)g,
        (__attribute__((address_space(3))) unsigned int*)s, 16, 0, 0);
}

// ---------------------------------------------------------------------------
// convX: f32 -> bf16 elementwise (n % 4 == 0)
// ---------------------------------------------------------------------------
__global__ void convX_kernel(const float* __restrict__ X, u16* __restrict__ Xb, int n)
{
    int i = (blockIdx.x * 256 + threadIdx.x) * 4;
    if (i >= n) return;
    float4 v = *(const float4*)(X + i);
    u16 o[4] = { f2bf(v.x), f2bf(v.y), f2bf(v.z), f2bf(v.w) };
    *(uint2*)(Xb + i) = *(uint2*)o;
}

// ---------------------------------------------------------------------------
// convT: W f32 [K][N] -> WT bf16 [N][K]  (LDS 32x32 tile transpose)
// ---------------------------------------------------------------------------
__global__ __launch_bounds__(256) void convT_kernel(
    const float* __restrict__ W, u16* __restrict__ WT, int K, int N)
{
    __shared__ float t[32][33];
    int n0 = blockIdx.x * 32, k0 = blockIdx.y * 32;
    int tx = threadIdx.x & 31, ty = threadIdx.x >> 5;
    for (int i = ty; i < 32; i += 8) {
        int k = k0 + i, n = n0 + tx;
        t[i][tx] = (k < K && n < N) ? W[(size_t)k * N + n] : 0.f;
    }
    __syncthreads();
    for (int i = ty; i < 32; i += 8) {
        int n = n0 + i, k = k0 + tx;
        if (n < N && k < K) WT[(size_t)n * K + k] = f2bf(t[tx][i]);
    }
}

// ---------------------------------------------------------------------------
// xmean
// ---------------------------------------------------------------------------
__global__ void xmean_kernel(const float* __restrict__ X, float* __restrict__ Xm)
{
    int c = blockIdx.x * 256 + threadIdx.x;
    if (c >= 2560) return;
    int g = blockIdx.y;
    const float* base = X + (size_t)g * 32 * 2560 + c;
    float s = 0.f;
#pragma unroll 4
    for (int j = 0; j < 32; j++) s += base[(size_t)j * 2560];
    Xm[(size_t)g * 2560 + c] = s * (1.f / 32.f);
}

// ---------------------------------------------------------------------------
// Split-precision GEMM (bf16x3 ~ f32): C = A[M,K]@B[K,N] + bias. (kmean only)
// ---------------------------------------------------------------------------
__global__ __launch_bounds__(256) void gemmS_kernel(
    const float* __restrict__ A, const float* __restrict__ B,
    const float* __restrict__ bias, int M, int N, int K, float* __restrict__ outf)
{
    __shared__ __align__(16) u16 Ah[64][32], Al[64][32];
    __shared__ __align__(16) u16 Bh[64][32], Bl[64][32];
    const int tid = threadIdx.x;
    const int bm = blockIdx.x * 64, bn = blockIdx.y * 64;
    const int w = tid >> 6, lane = tid & 63;
    const int quad = lane >> 4, l = lane & 15;
    v4f acc[4];
#pragma unroll
    for (int nt = 0; nt < 4; nt++)
#pragma unroll
        for (int r = 0; r < 4; r++) acc[nt][r] = 0.f;
    const int ar = tid >> 2, ak = (tid & 3) * 8;
    const int kr = tid >> 3, nc = (tid & 7) * 8;
    for (int k0 = 0; k0 < K; k0 += 32) {
        float4 a0 = *(const float4*)(A + (size_t)(bm + ar) * K + (k0 + ak));
        float4 a1 = *(const float4*)(A + (size_t)(bm + ar) * K + (k0 + ak) + 4);
        float4 b0 = *(const float4*)(B + (size_t)(k0 + kr) * N + (bn + nc));
        float4 b1 = *(const float4*)(B + (size_t)(k0 + kr) * N + (bn + nc) + 4);
        float av[8] = {a0.x,a0.y,a0.z,a0.w,a1.x,a1.y,a1.z,a1.w};
        float bv[8] = {b0.x,b0.y,b0.z,b0.w,b1.x,b1.y,b1.z,b1.w};
        __syncthreads();
#pragma unroll
        for (int j = 0; j < 8; j++) {
            u16 h = f2bf(av[j]);
            Ah[ar][ak + j] = h; Al[ar][ak + j] = f2bf(av[j] - bf2f(h));
            u16 g = f2bf(bv[j]);
            Bh[nc + j][kr] = g; Bl[nc + j][kr] = f2bf(bv[j] - bf2f(g));
        }
        __syncthreads();
        v8s ah = *(const v8s*)(&Ah[w * 16 + l][quad * 8]);
        v8s al = *(const v8s*)(&Al[w * 16 + l][quad * 8]);
#pragma unroll
        for (int nt = 0; nt < 4; nt++) {
            v8s bh = *(const v8s*)(&Bh[nt * 16 + l][quad * 8]);
            v8s bl = *(const v8s*)(&Bl[nt * 16 + l][quad * 8]);
            acc[nt] = __builtin_amdgcn_mfma_f32_16x16x32_bf16(ah, bh, acc[nt], 0, 0, 0);
            acc[nt] = __builtin_amdgcn_mfma_f32_16x16x32_bf16(ah, bl, acc[nt], 0, 0, 0);
            acc[nt] = __builtin_amdgcn_mfma_f32_16x16x32_bf16(al, bh, acc[nt], 0, 0, 0);
        }
    }
#pragma unroll
    for (int nt = 0; nt < 4; nt++) {
        int col = bn + nt * 16 + l;
        float bvs = bias[col];
#pragma unroll
        for (int r = 0; r < 4; r++) {
            int row = bm + w * 16 + quad * 4 + r;
            outf[(size_t)row * N + col] = scrub(acc[nt][r] + bvs);
        }
    }
}

// ---------------------------------------------------------------------------
// m1
// ---------------------------------------------------------------------------
__global__ __launch_bounds__(256) void m1_kernel(
    const float* __restrict__ Wq, const float* __restrict__ km,
    u16* __restrict__ M1hT, u16* __restrict__ M1lT)
{
    __shared__ float Ws[64][81];
    __shared__ float Ks[32][80];
    int k0 = blockIdx.x * 64, h = blockIdx.y, b = blockIdx.z;
    int tid = threadIdx.x;
    for (int i = tid; i < 64 * 80; i += 256) {
        int kk = i / 80, dd = i - kk * 80;
        Ws[kk][dd] = Wq[(size_t)(k0 + kk) * 2560 + h * 80 + dd];
    }
    for (int i = tid; i < 32 * 80; i += 256) {
        int bl = i / 80, dd = i - bl * 80;
        Ks[bl][dd] = km[(size_t)((b << 5) + bl) * 2560 + h * 80 + dd];
    }
    __syncthreads();
    int kk = tid & 63, bq4 = tid >> 6;
    for (int bt = 0; bt < 8; bt++) {
        int blk = bt * 4 + bq4;
        float s = 0.f;
#pragma unroll 8
        for (int d = 0; d < 80; d++) s += Ws[kk][d] * Ks[blk][d];
        u16 hi = f2bf(s);
        size_t o = (size_t)(b * 1024 + h * 32 + blk) * 2560 + k0 + kk;
        M1hT[o] = hi;
        M1lT[o] = f2bf(s - bf2f(hi));
    }
}

// bias3
__global__ void bias3_kernel(const float* __restrict__ bq, const float* __restrict__ km,
                             float* __restrict__ bias3)
{
    int i = blockIdx.x * 256 + threadIdx.x;
    if (i >= 2048) return;
    int b = i >> 10, hb = i & 1023, h = hb >> 5, blk = hb & 31;
    float s = 0.f;
    for (int d = 0; d < 80; d++) s += bq[h * 80 + d] * km[(size_t)((b << 5) + blk) * 2560 + h * 80 + d];
    bias3[i] = s;
}

// ---------------------------------------------------------------------------
// gemmS2: BS = A(f32, split inline) @ BT(pre-split bf16 [N][K])^T + bias -> f32
// 2-phase pipeline: B via glds16 double-buffer; A via register prefetch.
// ---------------------------------------------------------------------------
__global__ __launch_bounds__(256) void gemmS2_kernel(
    const float* __restrict__ A, const u16* __restrict__ BhT, const u16* __restrict__ BlT,
    const float* __restrict__ bias, int M, int N, int K, float* __restrict__ outf)
{
    __shared__ __align__(16) u16 Ah[2][64][32], Al[2][64][32];
    __shared__ __align__(16) u16 Bh[2][64][32], Bl[2][64][32];
    const int tid = threadIdx.x;
    const int z = blockIdx.z;
    const float* Az = A + (size_t)z * 1024 * 2560;
    const u16* Bhz = BhT + (size_t)z * 1024 * 2560;
    const u16* Blz = BlT + (size_t)z * 1024 * 2560;
    const float* biasz = bias + (size_t)z * 1024;
    float* outz = outf + (size_t)z * 1024 * 1024;
    const int bm = blockIdx.x * 64, bn = blockIdx.y * 64;
    const int w = tid >> 6, lane = tid & 63;
    const int quad = lane >> 4, l = lane & 15;
    v4f acc[4];
#pragma unroll
    for (int nt = 0; nt < 4; nt++)
#pragma unroll
        for (int r = 0; r < 4; r++) acc[nt][r] = 0.f;
    const int ar = tid >> 2, ak = (tid & 3) * 8;
    const float* ApF = Az + (size_t)(bm + ar) * K + ak;
    const u16* BpH = Bhz + (size_t)(bn + ar) * K + ak;
    const u16* BpL = Blz + (size_t)(bn + ar) * K + ak;
    char* BhB = (char*)Bh;
    char* BlB = (char*)Bl;
    const int NT = K >> 5;
    glds16(BpH, BhB + w * 1024);
    glds16(BpL, BlB + w * 1024);
    float4 a0 = *(const float4*)(ApF);
    float4 a1 = *(const float4*)(ApF + 4);
    __syncthreads();
    for (int t = 0; t < NT; t++) {
        const int cur = t & 1;
        const int nxt = cur ^ 1;
        if (t + 1 < NT) {
            int k0n = (t + 1) << 5;
            glds16(BpH + k0n, BhB + nxt * 4096 + w * 1024);
            glds16(BpL + k0n, BlB + nxt * 4096 + w * 1024);
        }
        float av[8] = {a0.x, a0.y, a0.z, a0.w, a1.x, a1.y, a1.z, a1.w};
        if (t + 1 < NT) {
            int k0n = (t + 1) << 5;
            a0 = *(const float4*)(ApF + k0n);
            a1 = *(const float4*)(ApF + k0n + 4);
        }
#pragma unroll
        for (int j = 0; j < 8; j++) {
            u16 h = f2bf(av[j]);
            Ah[cur][ar][ak + j] = h;
            Al[cur][ar][ak + j] = f2bf(av[j] - bf2f(h));
        }
        v8s ah = *(const v8s*)(&Ah[cur][w * 16 + l][quad * 8]);
        v8s al2 = *(const v8s*)(&Al[cur][w * 16 + l][quad * 8]);
#pragma unroll
        for (int nt = 0; nt < 4; nt++) {
            v8s bh = *(const v8s*)(&Bh[cur][nt * 16 + l][quad * 8]);
            v8s bl = *(const v8s*)(&Bl[cur][nt * 16 + l][quad * 8]);
            acc[nt] = __builtin_amdgcn_mfma_f32_16x16x32_bf16(ah, bh, acc[nt], 0, 0, 0);
            acc[nt] = __builtin_amdgcn_mfma_f32_16x16x32_bf16(ah, bl, acc[nt], 0, 0, 0);
            acc[nt] = __builtin_amdgcn_mfma_f32_16x16x32_bf16(al2, bh, acc[nt], 0, 0, 0);
        }
        __syncthreads();
    }
#pragma unroll
    for (int nt = 0; nt < 4; nt++) {
        int col = bn + nt * 16 + l;
        float bvs = biasz[col];
#pragma unroll
        for (int r = 0; r < 4; r++) {
            int row = bm + w * 16 + quad * 4 + r;
            outz[(size_t)row * N + col] = scrub(acc[nt][r] + bvs);
        }
    }
}

// ---------------------------------------------------------------------------
// gemmB: C = act(A[M,K]@BT[N,K]^T + bias). 2-phase glds16 double-buffer.
// ---------------------------------------------------------------------------
__global__ __launch_bounds__(256) void gemmB_kernel(
    const u16* __restrict__ A, const u16* __restrict__ Al2, const u16* __restrict__ BT,
    const float* __restrict__ bias, int M, int N, int K, int act, int ldc,
    u16* __restrict__ outb, float* __restrict__ outf, u16* __restrict__ outT)
{
    __shared__ __align__(16) u16 As[2][64][32];
    __shared__ __align__(16) u16 As2[2][64][32];
    __shared__ __align__(16) u16 Bs[2][64][32];
    const int tid = threadIdx.x;
    const int bm = blockIdx.x * 64, bn = blockIdx.y * 64;
    const int w = tid >> 6, lane = tid & 63;
    const int quad = lane >> 4, l = lane & 15;
    v4f acc[4];
#pragma unroll
    for (int nt = 0; nt < 4; nt++)
#pragma unroll
        for (int r = 0; r < 4; r++) acc[nt][r] = 0.f;
    const int srow = w * 16 + (lane >> 2);
    const int kcol = (lane & 3) * 8;
    const int brow = (bn + srow < N) ? (bn + srow) : (N - 1);
    const u16* Ap = A + (size_t)(bm + srow) * K + kcol;
    const u16* Bp = BT + (size_t)brow * K + kcol;
    const u16* A2p = Al2 ? (Al2 + (size_t)(bm + srow) * K + kcol) : nullptr;
    char* AsB = (char*)As;
    char* As2B = (char*)As2;
    char* BsB = (char*)Bs;
    const int NT = K >> 5;
    glds16(Ap, AsB + w * 1024);
    glds16(Bp, BsB + w * 1024);
    if (Al2) glds16(A2p, As2B + w * 1024);
    __syncthreads();
    for (int t = 0; t < NT; t++) {
        const int cur = t & 1;
        const int nxt = cur ^ 1;
        if (t + 1 < NT) {
            int k0n = (t + 1) << 5;
            glds16(Ap + k0n, AsB + nxt * 4096 + w * 1024);
            glds16(Bp + k0n, BsB + nxt * 4096 + w * 1024);
            if (Al2) glds16(A2p + k0n, As2B + nxt * 4096 + w * 1024);
        }
        v8s af = *(const v8s*)(&As[cur][w * 16 + l][quad * 8]);
#pragma unroll
        for (int nt = 0; nt < 4; nt++) {
            v8s bf = *(const v8s*)(&Bs[cur][nt * 16 + l][quad * 8]);
            acc[nt] = __builtin_amdgcn_mfma_f32_16x16x32_bf16(af, bf, acc[nt], 0, 0, 0);
        }
        if (Al2) {
            v8s af2 = *(const v8s*)(&As2[cur][w * 16 + l][quad * 8]);
#pragma unroll
            for (int nt = 0; nt < 4; nt++) {
                v8s bf = *(const v8s*)(&Bs[cur][nt * 16 + l][quad * 8]);
                acc[nt] = __builtin_amdgcn_mfma_f32_16x16x32_bf16(af2, bf, acc[nt], 0, 0, 0);
            }
        }
        __syncthreads();
    }
#pragma unroll
    for (int nt = 0; nt < 4; nt++) {
        int col = bn + nt * 16 + l;
        if (col < N) {
            float bvs = bias[col];
#pragma unroll
            for (int r = 0; r < 4; r++) {
                int row = bm + w * 16 + quad * 4 + r;
                float c = acc[nt][r] + bvs;
                if (act == 1) c = 0.5f * c * (1.0f + erff(c * 0.70710678118654752f));
                c = scrub(c);
                if (outf) outf[(size_t)row * ldc + col] = c;
                if (outb) outb[(size_t)row * ldc + col] = f2bf(c);
                if (outT) {
                    int bb = row >> 10, s = row & 1023;
                    int hh = col / 80, dd = col - hh * 80;
                    outT[((size_t)((bb << 5) + hh) * 96 + dd) * 1024 + s] = f2bf(c);
                }
            }
        }
    }
}

// ---------------------------------------------------------------------------
// gatherF / gatherFT
// ---------------------------------------------------------------------------
__global__ void gatherF_kernel(const u16* __restrict__ src, const float* __restrict__ pos,
                               u16* __restrict__ F)
{
    int row = blockIdx.y;
    int col = blockIdx.x * 256 + threadIdx.x;
    if (col >= 2560) return;
    int b = row >> 10, h = (row >> 5) & 31, blk = row & 31;
    int j = col / 80, d = col - j * 80;
    float v = bf2f(src[(size_t)(b * 1024 + blk * 32 + j) * 2560 + h * 80 + d]) + pos[col];
    F[(size_t)row * 2560 + col] = f2bf(v);
}
__global__ void gatherFT_kernel(const u16* __restrict__ vt, const float* __restrict__ pos,
                                u16* __restrict__ F)
{
    int row = blockIdx.y;
    int col = blockIdx.x * 256 + threadIdx.x;
    if (col >= 2560) return;
    int b = row >> 10, h = (row >> 5) & 31, blk = row & 31;
    int j = col / 80, d = col - j * 80;
    float v = bf2f(vt[((size_t)((b << 5) + h) * 96 + d) * 1024 + blk * 32 + j]) + pos[col];
    F[(size_t)row * 2560 + col] = f2bf(v);
}

// ---------------------------------------------------------------------------
// gates
// ---------------------------------------------------------------------------
__global__ __launch_bounds__(256) void gates_kernel(
    const u16* __restrict__ gh, const float* __restrict__ W2,
    const float* __restrict__ b2, float* __restrict__ gates)
{
    int w = threadIdx.x >> 6, lane = threadIdx.x & 63;
    int token = blockIdx.x * 4 + w;
    float s0 = 0.f, s1 = 0.f, s2 = 0.f;
    for (int i = lane; i < 1280; i += 64) {
        float g = bf2f(gh[(size_t)token * 1280 + i]);
        s0 += g * W2[i * 3 + 0];
        s1 += g * W2[i * 3 + 1];
        s2 += g * W2[i * 3 + 2];
    }
#pragma unroll
    for (int m = 1; m < 64; m <<= 1) {
        s0 += __shfl_xor(s0, m);
        s1 += __shfl_xor(s1, m);
        s2 += __shfl_xor(s2, m);
    }
    if (lane == 0) {
        gates[token * 3 + 0] = scrub(1.f / (1.f + expf(-(s0 + b2[0]))));
        gates[token * 3 + 1] = scrub(1.f / (1.f + expf(-(s1 + b2[1]))));
        gates[token * 3 + 2] = scrub(1.f / (1.f + expf(-(s2 + b2[2]))));
    }
}

// ---------------------------------------------------------------------------
// Fused NSA attention v7: v3 structure (R5 best, 271us) + XCD-aware swizzle.
// 1-D grid of 4096; block id decoded so all 64 qt-tiles of a head land on the
// same XCD (bid%8 == bh%8 under round-robin dispatch). Per-XCD L2 working set
// drops ~21MB -> ~5MB (8 heads x {K-slice 160KB, V 192KB, Q 160KB}).
// ---------------------------------------------------------------------------
__global__ __launch_bounds__(64) void attn_kernel(
    const u16* __restrict__ qb, const u16* __restrict__ kbf,
    const u16* __restrict__ vt, const u16* __restrict__ kc,
    const u16* __restrict__ vc, const float* __restrict__ BSf,
    const float* __restrict__ gates, u16* __restrict__ comb, u16* __restrict__ combl)
{
    const int lane = threadIdx.x, quad = lane >> 4, l = lane & 15;
    // XCD swizzle: bid = (bh&7) + 8*(qt + 64*(bh>>3)); bijective for 4096.
    const int bid = blockIdx.x;
    const int xcd = bid & 7;
    const int rest = bid >> 3;
    const int qt = rest & 63;
    const int bh = xcd + ((rest >> 6) << 3);
    const int b = bh >> 5, h = bh & 31;
    const float NEG = -1e30f;

    __shared__ float bs[16][33];
    __shared__ unsigned int selmask[16];
    __shared__ __align__(16) u16 Pw[16][40];
    __shared__ float ocn[16][80];

    // ---- block scores from precomputed BS (f32-accurate) ----
    {
        const float* bsrow = BSf + ((size_t)b * 1024 + qt * 16 + l) * 1024 + h * 32 + quad * 8;
#pragma unroll
        for (int i = 0; i < 8; i++) bs[l][quad * 8 + i] = bsrow[i] * SCALE_F;
    }
    __syncthreads();
    if (lane < 16) {
        unsigned int mask = 0u;
        for (int it = 0; it < 16; it++) {
            float best = NEG; int bi = -1;
            for (int n = 0; n < 32; n++) {
                if (((mask >> n) & 1u) == 0u && bs[lane][n] > best) { best = bs[lane][n]; bi = n; }
            }
            if (bi < 0) { for (int n = 0; n < 32; n++) if (((mask >> n) & 1u) == 0u) { bi = n; break; } }
            mask |= (1u << bi);
        }
        selmask[lane] = mask;
    }
    __syncthreads();
    const unsigned int selm_l = selmask[l];   // mask for PV A-fragment row (query l)
    unsigned int selm[4];
#pragma unroll
    for (int r = 0; r < 4; r++) selm[r] = selmask[quad * 4 + r];  // mask for C-row q=quad*4+r

    // ---- Q fragments ----
    v8s qfrag[3];
    {
        const u16* qrow = qb + (size_t)(b * 1024 + qt * 16 + l) * 2560 + h * 80;
#pragma unroll
        for (int c = 0; c < 3; c++) {
            if (c == 2 && quad >= 2) { qfrag[c] = zero8(); }
            else qfrag[c] = *(const v8s*)(qrow + c * 32 + quad * 8);
        }
    }

    // ---- compressed branch; result normalized+g0-folded into ocn LDS ----
    {
        v4f oc[5];
#pragma unroll
        for (int t = 0; t < 5; t++)
#pragma unroll
            for (int r = 0; r < 4; r++) oc[t][r] = 0.f;
        float l_c[4];
        v4f s0, s1;
#pragma unroll
        for (int r = 0; r < 4; r++) { s0[r] = 0.f; s1[r] = 0.f; }
#pragma unroll
        for (int c = 0; c < 3; c++) {
            v8s b0, b1;
            if (c == 2 && quad >= 2) { b0 = zero8(); b1 = zero8(); }
            else {
                b0 = *(const v8s*)(kc + (size_t)(bh * 32 + l) * 80 + c * 32 + quad * 8);
                b1 = *(const v8s*)(kc + (size_t)(bh * 32 + 16 + l) * 80 + c * 32 + quad * 8);
            }
            s0 = __builtin_amdgcn_mfma_f32_16x16x32_bf16(qfrag[c], b0, s0, 0, 0, 0);
            s1 = __builtin_amdgcn_mfma_f32_16x16x32_bf16(qfrag[c], b1, s1, 0, 0, 0);
        }
#pragma unroll
        for (int r = 0; r < 4; r++) {
            float x0 = s0[r] * SCALE_L2, x1 = s1[r] * SCALE_L2;
            float mx = fmaxf(x0, x1);
#pragma unroll
            for (int m = 1; m < 16; m <<= 1) mx = fmaxf(mx, __shfl_xor(mx, m));
            float p0 = exp2f(x0 - mx), p1 = exp2f(x1 - mx);
            float sm = p0 + p1;
#pragma unroll
            for (int m = 1; m < 16; m <<= 1) sm += __shfl_xor(sm, m);
            l_c[r] = sm;
            Pw[quad * 4 + r][l]      = f2bf(p0);
            Pw[quad * 4 + r][l + 16] = f2bf(p1);
        }
        __syncthreads();
        v8s pa = *(const v8s*)(&Pw[l][quad * 8]);
#pragma unroll
        for (int t = 0; t < 5; t++) {
            union { v8s v; short s[8]; } vf;
#pragma unroll
            for (int j = 0; j < 8; j++)
                vf.s[j] = (short)vc[(size_t)(bh * 32 + quad * 8 + j) * 80 + t * 16 + l];
            oc[t] = __builtin_amdgcn_mfma_f32_16x16x32_bf16(pa, vf.v, oc[t], 0, 0, 0);
        }
#pragma unroll
        for (int r = 0; r < 4; r++) {
            int token = b * 1024 + qt * 16 + quad * 4 + r;
            float g0 = gates[token * 3 + 0];
            float fc = g0 / fmaxf(l_c[r], 1e-30f);
#pragma unroll
            for (int t = 0; t < 5; t++) ocn[quad * 4 + r][t * 16 + l] = oc[t][r] * fc;
        }
        __syncthreads();
    }

    // ---- flash loop: window + selection (shared stabilizer, defer-max) ----
    v4f aw[5], as_[5];
    float m_w[4], l_w[4], l_s[4];
#pragma unroll
    for (int r = 0; r < 4; r++) { m_w[r] = NEG; l_w[r] = 0.f; l_s[r] = 0.f; }
#pragma unroll
    for (int t = 0; t < 5; t++)
#pragma unroll
        for (int r = 0; r < 4; r++) { aw[t][r] = 0.f; as_[t][r] = 0.f; }

    const u16* vtp = vt + (size_t)bh * 96 * 1024;

    for (int kb = 0; kb < 32; kb++) {
        v4f s0, s1;
#pragma unroll
        for (int r = 0; r < 4; r++) { s0[r] = 0.f; s1[r] = 0.f; }
#pragma unroll
        for (int c = 0; c < 3; c++) {
            v8s k0f, k1f;
            if (c == 2 && quad >= 2) { k0f = zero8(); k1f = zero8(); }
            else {
                size_t base = (size_t)(b * 1024 + kb * 32) * 2560 + h * 80 + c * 32 + quad * 8;
                k0f = *(const v8s*)(kbf + base + (size_t)l * 2560);
                k1f = *(const v8s*)(kbf + base + (size_t)(16 + l) * 2560);
            }
            s0 = __builtin_amdgcn_mfma_f32_16x16x32_bf16(qfrag[c], k0f, s0, 0, 0, 0);
            s1 = __builtin_amdgcn_mfma_f32_16x16x32_bf16(qfrag[c], k1f, s1, 0, 0, 0);
        }
        float x0a[4], x1a[4], pmax[4];
        float needmax = NEG;
#pragma unroll
        for (int r = 0; r < 4; r++) {
            x0a[r] = s0[r] * SCALE_L2; x1a[r] = s1[r] * SCALE_L2;
            float mb = fmaxf(x0a[r], x1a[r]);
#pragma unroll
            for (int m = 1; m < 16; m <<= 1) mb = fmaxf(mb, __shfl_xor(mb, m));
            pmax[r] = mb;
            needmax = fmaxf(needmax, mb - m_w[r]);
        }
        if (__all(needmax <= 8.0f)) {
            // defer-max: keep old stabilizer, no rescale (P bounded by 2^8)
#pragma unroll
            for (int r = 0; r < 4; r++) {
                float p0 = exp2f(x0a[r] - m_w[r]), p1 = exp2f(x1a[r] - m_w[r]);
                Pw[quad * 4 + r][l]      = f2bf(p0);
                Pw[quad * 4 + r][l + 16] = f2bf(p1);
                float st = p0 + p1;
#pragma unroll
                for (int m = 1; m < 16; m <<= 1) st += __shfl_xor(st, m);
                l_w[r] += st;
                if ((selm[r] >> kb) & 1u) l_s[r] += st;
            }
        } else {
            float alw[4];
#pragma unroll
            for (int r = 0; r < 4; r++) {
                float mn = fmaxf(m_w[r], pmax[r]);
                alw[r] = exp2f(m_w[r] - mn);
                m_w[r] = mn;
                float p0 = exp2f(x0a[r] - mn), p1 = exp2f(x1a[r] - mn);
                Pw[quad * 4 + r][l]      = f2bf(p0);
                Pw[quad * 4 + r][l + 16] = f2bf(p1);
                float st = p0 + p1;
#pragma unroll
                for (int m = 1; m < 16; m <<= 1) st += __shfl_xor(st, m);
                l_w[r] = l_w[r] * alw[r] + st;
                l_s[r] = l_s[r] * alw[r] + (((selm[r] >> kb) & 1u) ? st : 0.f);
            }
#pragma unroll
            for (int t = 0; t < 5; t++)
#pragma unroll
                for (int r = 0; r < 4; r++) { aw[t][r] *= alw[r]; as_[t][r] *= alw[r]; }
        }
        __syncthreads();
        v8s pwa = *(const v8s*)(&Pw[l][quad * 8]);
        v8s psa = ((selm_l >> kb) & 1u) ? pwa : zero8();
#pragma unroll
        for (int t = 0; t < 5; t++) {
            v8s vfr = *(const v8s*)(vtp + ((size_t)(t * 16 + l)) * 1024 + kb * 32 + quad * 8);
            aw[t]  = __builtin_amdgcn_mfma_f32_16x16x32_bf16(pwa, vfr, aw[t], 0, 0, 0);
            as_[t] = __builtin_amdgcn_mfma_f32_16x16x32_bf16(psa, vfr, as_[t], 0, 0, 0);
        }
        __syncthreads();
    }

    // ---- gate-combine + split store ----
#pragma unroll
    for (int r = 0; r < 4; r++) {
        int token = b * 1024 + qt * 16 + quad * 4 + r;
        float g1 = gates[token * 3 + 1], g2 = gates[token * 3 + 2];
        float fw = g2 / fmaxf(l_w[r], 1e-30f);
        float fs = g1 / fmaxf(l_s[r], 1e-30f);
#pragma unroll
        for (int t = 0; t < 5; t++) {
            float val = ocn[quad * 4 + r][t * 16 + l] + fs * as_[t][r] + fw * aw[t][r];
            val = scrub(val);
            u16 hi = f2bf(val);
            size_t o = (size_t)token * 2560 + h * 80 + t * 16 + l;
            comb[o] = hi;
            combl[o] = f2bf(val - bf2f(hi));
        }
    }
}

// ---------------------------------------------------------------------------
extern "C" void kernel_launch(void* const* d_in, const int* in_sizes, int n_in,
                              void* d_out, int out_size, void* d_ws, size_t ws_size,
                              hipStream_t stream)
{
    (void)in_sizes; (void)n_in; (void)out_size; (void)ws_size;

    const float* X   = (const float*)d_in[0];
    const float* Wq  = (const float*)d_in[1];
    const float* bq  = (const float*)d_in[2];
    const float* Wk  = (const float*)d_in[3];
    const float* bk  = (const float*)d_in[4];
    const float* Wv  = (const float*)d_in[5];
    const float* bv  = (const float*)d_in[6];
    const float* Wo  = (const float*)d_in[7];
    const float* bo  = (const float*)d_in[8];
    const float* pos = (const float*)d_in[9];
    const float* cW1 = (const float*)d_in[10];
    const float* cb1 = (const float*)d_in[11];
    const float* cW2 = (const float*)d_in[12];
    const float* cb2 = (const float*)d_in[13];
    const float* gW1 = (const float*)d_in[14];
    const float* gb1 = (const float*)d_in[15];
    const float* gW2 = (const float*)d_in[16];
    const float* gb2 = (const float*)d_in[17];

    char* ws = (char*)d_ws;
    size_t off = 0;
    auto alloc = [&](size_t bytes) -> void* {
        void* p = ws + off;
        off += (bytes + 255) & ~(size_t)255;
        return p;
    };
    u16*   Xb     = (u16*)  alloc(2048ull * 2560 * 2);
    u16*   WqT    = (u16*)  alloc(2560ull * 2560 * 2);
    u16*   WkT    = (u16*)  alloc(2560ull * 2560 * 2);
    u16*   WvT    = (u16*)  alloc(2560ull * 2560 * 2);
    u16*   WoT    = (u16*)  alloc(2560ull * 2560 * 2);
    u16*   gW1T   = (u16*)  alloc(1280ull * 2560 * 2);
    u16*   cW1T   = (u16*)  alloc(320ull * 2560 * 2);
    u16*   cW2T   = (u16*)  alloc(96ull * 320 * 2);
    float* Xm     = (float*)alloc(64ull * 2560 * 4);
    float* kmeanS = (float*)alloc(64ull * 2560 * 4);
    u16*   M1hT   = (u16*)  alloc(2048ull * 2560 * 2);
    u16*   M1lT   = (u16*)  alloc(2048ull * 2560 * 2);
    float* bias3  = (float*)alloc(2048ull * 4);
    u16*   qbuf   = (u16*)  alloc(2048ull * 2560 * 2);
    u16*   kbf    = (u16*)  alloc(2048ull * 2560 * 2);
    u16*   vtb    = (u16*)  alloc(64ull * 96 * 1024 * 2);
    u16*   combl  = (u16*)  alloc(2048ull * 2560 * 2);
    char*  R1     = (char*) alloc(12ull * 1024 * 1024);
    u16*   gh     = (u16*)R1;
    u16*   Fb     = (u16*)R1;
    u16*   H1     = (u16*)(R1 + 10ull * 1024 * 1024);
    u16*   combb  = (u16*)R1;
    u16*   KC     = (u16*)  alloc(2048ull * 80 * 2);
    u16*   VC     = (u16*)  alloc(2048ull * 80 * 2);
    float* gatesf = (float*)alloc(2048ull * 3 * 4);
    float* BSf    = (float*)d_out;

    dim3 blk(256);
    convX_kernel<<<2048 * 2560 / 4 / 256, blk, 0, stream>>>(X, Xb, 2048 * 2560);
    convT_kernel<<<dim3(80, 80), blk, 0, stream>>>(Wq, WqT, 2560, 2560);
    convT_kernel<<<dim3(80, 80), blk, 0, stream>>>(Wk, WkT, 2560, 2560);
    convT_kernel<<<dim3(80, 80), blk, 0, stream>>>(Wv, WvT, 2560, 2560);
    convT_kernel<<<dim3(80, 80), blk, 0, stream>>>(Wo, WoT, 2560, 2560);
    convT_kernel<<<dim3(40, 80), blk, 0, stream>>>(gW1, gW1T, 2560, 1280);
    convT_kernel<<<dim3(10, 80), blk, 0, stream>>>(cW1, cW1T, 2560, 320);
    convT_kernel<<<dim3(3, 10), blk, 0, stream>>>(cW2, cW2T, 320, 80);
    xmean_kernel<<<dim3(10, 64), blk, 0, stream>>>(X, Xm);
    gemmS_kernel<<<dim3(1, 40), blk, 0, stream>>>(Xm, Wk, bk, 64, 2560, 2560, kmeanS);
    m1_kernel<<<dim3(40, 32, 2), blk, 0, stream>>>(Wq, kmeanS, M1hT, M1lT);
    bias3_kernel<<<8, blk, 0, stream>>>(bq, kmeanS, bias3);
    gemmS2_kernel<<<dim3(16, 16, 2), blk, 0, stream>>>(X, M1hT, M1lT, bias3, 1024, 1024, 2560, BSf);
    gemmB_kernel<<<dim3(32, 40), blk, 0, stream>>>(Xb, nullptr, WqT, bq, 2048, 2560, 2560, 0, 2560, qbuf, nullptr, nullptr);
    gemmB_kernel<<<dim3(32, 40), blk, 0, stream>>>(Xb, nullptr, WkT, bk, 2048, 2560, 2560, 0, 2560, kbf, nullptr, nullptr);
    gemmB_kernel<<<dim3(32, 40), blk, 0, stream>>>(Xb, nullptr, WvT, bv, 2048, 2560, 2560, 0, 2560, nullptr, nullptr, vtb);
    gemmB_kernel<<<dim3(32, 20), blk, 0, stream>>>(Xb, nullptr, gW1T, gb1, 2048, 1280, 2560, 1, 1280, gh, nullptr, nullptr);
    gates_kernel<<<512, blk, 0, stream>>>(gh, gW2, gb2, gatesf);
    gatherF_kernel<<<dim3(10, 2048), blk, 0, stream>>>(kbf, pos, Fb);
    gemmB_kernel<<<dim3(32, 5), blk, 0, stream>>>(Fb, nullptr, cW1T, cb1, 2048, 320, 2560, 1, 320, H1, nullptr, nullptr);
    gemmB_kernel<<<dim3(32, 2), blk, 0, stream>>>(H1, nullptr, cW2T, cb2, 2048, 80, 320, 0, 80, KC, nullptr, nullptr);
    gatherFT_kernel<<<dim3(10, 2048), blk, 0, stream>>>(vtb, pos, Fb);
    gemmB_kernel<<<dim3(32, 5), blk, 0, stream>>>(Fb, nullptr, cW1T, cb1, 2048, 320, 2560, 1, 320, H1, nullptr, nullptr);
    gemmB_kernel<<<dim3(32, 2), blk, 0, stream>>>(H1, nullptr, cW2T, cb2, 2048, 80, 320, 0, 80, VC, nullptr, nullptr);
    attn_kernel<<<dim3(4096), 64, 0, stream>>>(qbuf, kbf, vtb, KC, VC, BSf, gatesf, combb, combl);
    gemmB_kernel<<<dim3(32, 40), blk, 0, stream>>>(combb, combl, WoT, bo, 2048, 2560, 2560, 0, 2560, nullptr, (float*)d_out, nullptr);
}